// Round 2
// baseline (1150.141 us; speedup 1.0000x reference)
//
#include <hip/hip_runtime.h>

#define DEV __device__ __forceinline__
typedef unsigned int u32;
typedef unsigned short u16;
typedef __attribute__((ext_vector_type(8))) __bf16 bf16x8;
typedef __attribute__((ext_vector_type(4))) float f32x4;

#define MFMA16(a,b,c) __builtin_amdgcn_mfma_f32_16x16x32_bf16(a,b,c,0,0,0)

DEV u16 f2bf(float f){ u32 u=__float_as_uint(f); u32 r=(u+0x7fffu+((u>>16)&1u))>>16; return (u16)r; }
DEV float bf2f(u16 h){ return __uint_as_float(((u32)h)<<16); }

DEV void gload16(const void* g, void* l){
  __builtin_amdgcn_global_load_lds((const __attribute__((address_space(1))) void*)g,
                                   (__attribute__((address_space(3))) void*)l, 16, 0, 0);
}

// ---------------- prep kernels ----------------

// x (fp32) -> hi (+ lo if SPLIT) bf16, same layout
template<bool SPLIT>
__global__ void k_split(const float* __restrict__ in, u16* __restrict__ hi, u16* __restrict__ lo){
  size_t i=((size_t)blockIdx.x*256+threadIdx.x)*4;
  float4 v=*(const float4*)(in+i);
  u16 h0=f2bf(v.x),h1=f2bf(v.y),h2=f2bf(v.z),h3=f2bf(v.w);
  uint2 hh; hh.x=(u32)h0|((u32)h1<<16); hh.y=(u32)h2|((u32)h3<<16);
  *(uint2*)(hi+i)=hh;
  if constexpr(SPLIT){
    uint2 ll; ll.x=(u32)f2bf(v.x-bf2f(h0))|((u32)f2bf(v.y-bf2f(h1))<<16);
    ll.y=(u32)f2bf(v.z-bf2f(h2))|((u32)f2bf(v.w-bf2f(h3))<<16);
    *(uint2*)(lo+i)=ll;
  }
}

// W [K][N] fp32 -> W^T [N][K] hi (+ lo) bf16 (LDS-tiled transpose)
template<bool SPLIT>
__global__ void k_trans_split(const float* __restrict__ W, u16* __restrict__ hiT, u16* __restrict__ loT){
  __shared__ float t[64][65];
  const int tid=threadIdx.x;
  const int kb=blockIdx.y*64, nb=blockIdx.x*64;
  for(int p=0;p<4;p++){
    int r=(tid>>4)+p*16, c=(tid&15)*4;
    float4 v=*(const float4*)(W+(size_t)(kb+r)*4096+nb+c);
    t[r][c]=v.x;t[r][c+1]=v.y;t[r][c+2]=v.z;t[r][c+3]=v.w;
  }
  __syncthreads();
  for(int p=0;p<4;p++){
    int orow=(tid>>4)+p*16, oc=(tid&15)*4;
    u16 hs[4],ls[4];
    for(int j=0;j<4;j++){
      float x=t[oc+j][orow];
      hs[j]=f2bf(x); ls[j]=f2bf(x-bf2f(hs[j]));
    }
    uint2 uh; uh.x=(u32)hs[0]|((u32)hs[1]<<16); uh.y=(u32)hs[2]|((u32)hs[3]<<16);
    *(uint2*)(hiT+(size_t)(nb+orow)*4096+kb+oc)=uh;
    if constexpr(SPLIT){
      uint2 ul; ul.x=(u32)ls[0]|((u32)ls[1]<<16); ul.y=(u32)ls[2]|((u32)ls[3]<<16);
      *(uint2*)(loT+(size_t)(nb+orow)*4096+kb+oc)=ul;
    }
  }
}

// RoPE tables: [2048][64] cos, sin
__global__ void k_rope_tab(float* __restrict__ cosT, float* __restrict__ sinT){
  int i=blockIdx.x*256+threadIdx.x;           // 131072 total
  int s=i>>6, f=i&63;
  float inv=powf(10000.f, -(float)(2*f)/128.f);
  float ang=(float)s*inv;
  cosT[i]=cosf(ang); sinT[i]=sinf(ang);
}

// ---------------- split-precision GEMM (m97 structure) ----------------
// C[m][n] = sum_k A[m][k]*BT[n][k], 4096^3, A/BT stored hi(+lo) bf16.
// EPI 1: RoPE + store into [B,H,S,HD] (q/k).  EPI 2: store row-major (v^T).
// EPI 3: fp32 store (final output).
template<int EPI, bool SPLIT>
__global__ __launch_bounds__(256,2) void k_gemm(
    const u16* __restrict__ Ah, const u16* __restrict__ Al,
    const u16* __restrict__ Bh, const u16* __restrict__ Bl,
    float* __restrict__ outF, u16* __restrict__ outH, u16* __restrict__ outL,
    const float* __restrict__ cosT, const float* __restrict__ sinT)
{
  __shared__ u16 lds[4][4096];   // A_hi, A_lo, B_hi, B_lo : 128x32 each
  const int tid=threadIdx.x, lane=tid&63, w=tid>>6;
  const int m0=blockIdx.y*128, n0=blockIdx.x*128;
  const int wm=(w>>1)*64, wn=(w&1)*64;
  const f32x4 zero4={0.f,0.f,0.f,0.f};
  f32x4 acc[4][4];
  for(int m=0;m<4;m++)for(int n=0;n<4;n++)acc[m][n]=zero4;
  const int srow=lane>>2, soff=(lane&3)*8;
  for(int k0=0;k0<4096;k0+=32){
    for(int q8=w;q8<8;q8+=4){
      int r=q8*16+srow;
      size_t ao=(size_t)(m0+r)*4096+k0+soff;
      size_t bo=(size_t)(n0+r)*4096+k0+soff;
      gload16(Ah+ao,(char*)&lds[0][0]+q8*1024);
      gload16(Bh+bo,(char*)&lds[2][0]+q8*1024);
      if constexpr(SPLIT){
        gload16(Al+ao,(char*)&lds[1][0]+q8*1024);
        gload16(Bl+bo,(char*)&lds[3][0]+q8*1024);
      }
    }
    __syncthreads();
    const int fr=lane&15, fo=(lane>>4)*8;
    bf16x8 ah[4],al[4],bh[4],bl[4];
    for(int m=0;m<4;m++){
      int r=wm+m*16+fr;
      ah[m]=*(const bf16x8*)&lds[0][r*32+fo];
      if constexpr(SPLIT) al[m]=*(const bf16x8*)&lds[1][r*32+fo];
    }
    for(int n=0;n<4;n++){
      int r=wn+n*16+fr;
      bh[n]=*(const bf16x8*)&lds[2][r*32+fo];
      if constexpr(SPLIT) bl[n]=*(const bf16x8*)&lds[3][r*32+fo];
    }
    for(int m=0;m<4;m++)for(int n=0;n<4;n++){
      f32x4 c=acc[m][n];
      c=MFMA16(ah[m],bh[n],c);
      if constexpr(SPLIT){
        c=MFMA16(ah[m],bl[n],c);
        c=MFMA16(al[m],bh[n],c);
      }
      acc[m][n]=c;
    }
    __syncthreads();
  }
  for(int m=0;m<4;m++)for(int n=0;n<4;n++){
    int col=n0+wn+n*16+(lane&15);
    for(int r=0;r<4;r++){
      int row=m0+wm+m*16+(lane>>4)*4+r;
      float v=acc[m][n][r];
      if constexpr(EPI==1){
        int b=row>>11, s=row&2047, hd=col&127, hh=col>>7;
        float part=__shfl_xor(v,1);
        int fi=hd>>1;
        float cs=cosT[s*64+fi], sn=sinT[s*64+fi];
        float o=(hd&1)?(part*sn+v*cs):(v*cs-part*sn);
        u16 hb=f2bf(o);
        size_t addr=((size_t)(b*32+hh)*2048+s)*128+hd;
        outH[addr]=hb;
        if constexpr(SPLIT) outL[addr]=f2bf(o-bf2f(hb));
      } else if constexpr(EPI==2){
        u16 hb=f2bf(v);
        size_t addr=(size_t)row*4096+col;
        outH[addr]=hb;
        if constexpr(SPLIT) outL[addr]=f2bf(v-bf2f(hb));
      } else {
        outF[(size_t)row*4096+col]=v;
      }
    }
  }
}

// ---------------- flash attention ----------------
// grid (S/64, H, B), 256 threads. Wave w owns q rows [q0+16w, q0+16w+16).
// Q/K: [B,H,S,HD] hi(+lo) bf16.  V^T: [4096=d][4096=b*2048+s] hi(+lo) bf16.
// Swapped QK^T (mfma(K,Q) -> S^T, q=lane&15). XOR-swizzled LDS everywhere.
template<bool SPLIT>
__global__ __launch_bounds__(256,2) void k_attn(
    const u16* __restrict__ Qh, const u16* __restrict__ Ql,
    const u16* __restrict__ Kh, const u16* __restrict__ Kl,
    const u16* __restrict__ VTh, const u16* __restrict__ VTl,
    u16* __restrict__ Oh, u16* __restrict__ Ol)
{
  __shared__ u16 kvh[8192], kvl[8192];     // time-shared: K [64][128] then V^T [128][64]
  __shared__ u16 pbuf[4][2][1024];         // per-wave P [16 q][64 kv] hi/lo
  const int tid=threadIdx.x, lane=tid&63, w=tid>>6;
  const int q0=blockIdx.x*64, hh=blockIdx.y, b=blockIdx.z;
  const size_t headoff=((size_t)(b*32+hh))*2048*128;
  bf16x8 qh[4],ql[4];
  {
    int qr=q0+w*16+(lane&15);
    for(int c=0;c<4;c++){
      size_t a=headoff+(size_t)qr*128+(lane>>4)*8+32*c;
      qh[c]=*(const bf16x8*)(Qh+a);
      if constexpr(SPLIT) ql[c]=*(const bf16x8*)(Ql+a);
    }
  }
  const f32x4 zero4={0.f,0.f,0.f,0.f};
  f32x4 O[8]; for(int i=0;i<8;i++)O[i]=zero4;
  float m_run=-__builtin_inff(), l_run=0.f;
  const int nt=q0/64+1;
  const int qg=q0+w*16+(lane&15);
  const float scale=0.08838834764831845f;  // 1/sqrt(128)
  for(int t=0;t<nt;t++){
    const int kv0=t*64;
    // stage K (hi,lo): LDS [64][128] with byte^=((row&7)<<4) swizzle via pre-swizzled src
    for(int ch=w*4;ch<w*4+4;++ch){
      int p=ch*1024+lane*16;
      int row=p>>8, slot=(p>>4)&15, ss=slot^(row&7);
      size_t src=headoff+(size_t)(kv0+row)*128+ss*8;
      gload16(Kh+src,(char*)kvh+ch*1024);
      if constexpr(SPLIT) gload16(Kl+src,(char*)kvl+ch*1024);
    }
    __syncthreads();
    // QK^T: S^T[kv][q]
    f32x4 st[4]; for(int m=0;m<4;m++)st[m]=zero4;
    for(int c=0;c<4;c++){
      for(int m=0;m<4;m++){
        int row=m*16+(lane&15);
        int off=(((lane>>4)*16)+64*c)^((row&7)<<4);
        bf16x8 k8h=*(const bf16x8*)((const char*)kvh+row*256+off);
        st[m]=MFMA16(k8h,qh[c],st[m]);
        if constexpr(SPLIT){
          bf16x8 k8l=*(const bf16x8*)((const char*)kvl+row*256+off);
          st[m]=MFMA16(k8h,ql[c],st[m]);
          st[m]=MFMA16(k8l,qh[c],st[m]);
        }
      }
    }
    __syncthreads();
    // stage V^T (hi,lo): LDS [128][64], swizzled; overlaps with softmax below
    for(int ch=w*4;ch<w*4+4;++ch){
      int p=ch*1024+lane*16;
      int row=p>>7, slot=(p>>4)&7, ps=slot^(row&7);
      size_t src=(size_t)(hh*128+row)*4096+(size_t)b*2048+kv0+ps*8;
      gload16(VTh+src,(char*)kvh+ch*1024);
      if constexpr(SPLIT) gload16(VTl+src,(char*)kvl+ch*1024);
    }
    // online softmax (q = lane&15, kv spread over 4 lane-groups x 4 regs)
    float pm=-__builtin_inff();
    for(int m=0;m<4;m++)for(int r=0;r<4;r++){
      float sv=st[m][r]*scale;
      int kv=kv0+m*16+(lane>>4)*4+r;
      if(kv>qg)sv=-__builtin_inff();
      st[m][r]=sv;
      pm=fmaxf(pm,sv);
    }
    pm=fmaxf(pm,__shfl_xor(pm,16));
    pm=fmaxf(pm,__shfl_xor(pm,32));
    float m_new=fmaxf(m_run,pm);
    float corr=__expf(m_run-m_new);
    float psum=0.f;
    for(int m=0;m<4;m++){
      u16 ph[4],pl[4];
      for(int r=0;r<4;r++){
        float p=__expf(st[m][r]-m_new);
        psum+=p;
        ph[r]=f2bf(p); pl[r]=f2bf(p-bf2f(ph[r]));
      }
      int q=lane&15;
      int off=((m*32)+((lane>>4)*8))^((q&7)<<4);
      uint2 uh; uh.x=(u32)ph[0]|((u32)ph[1]<<16); uh.y=(u32)ph[2]|((u32)ph[3]<<16);
      *(uint2*)((char*)&pbuf[w][0][0]+q*128+off)=uh;
      if constexpr(SPLIT){
        uint2 ul; ul.x=(u32)pl[0]|((u32)pl[1]<<16); ul.y=(u32)pl[2]|((u32)pl[3]<<16);
        *(uint2*)((char*)&pbuf[w][1][0]+q*128+off)=ul;
      }
    }
    psum+=__shfl_xor(psum,16);
    psum+=__shfl_xor(psum,32);
    l_run=l_run*corr+psum;
    m_run=m_new;
    float cb[4];
    for(int r=0;r<4;r++)cb[r]=__shfl(corr,(lane>>4)*4+r);
    for(int nb=0;nb<8;nb++)for(int r=0;r<4;r++)O[nb][r]*=cb[r];
    __syncthreads();
    // PV: O[q][d] += P[q][kv] @ V[kv][d]
    for(int c2=0;c2<2;c2++){
      int q=lane&15;
      int offp=(((lane>>4)*16)+64*c2)^((q&7)<<4);
      bf16x8 pah=*(const bf16x8*)((const char*)&pbuf[w][0][0]+q*128+offp);
      for(int nb=0;nb<8;nb++){
        int vrow=nb*16+(lane&15);
        int voff=(((lane>>4)*16)+64*c2)^((vrow&7)<<4);
        bf16x8 v8h=*(const bf16x8*)((const char*)kvh+vrow*128+voff);
        O[nb]=MFMA16(pah,v8h,O[nb]);
        if constexpr(SPLIT){
          bf16x8 pal=*(const bf16x8*)((const char*)&pbuf[w][1][0]+q*128+offp);
          bf16x8 v8l=*(const bf16x8*)((const char*)kvl+vrow*128+voff);
          O[nb]=MFMA16(pah,v8l,O[nb]);
          O[nb]=MFMA16(pal,v8h,O[nb]);
        }
      }
    }
    __syncthreads();
  }
  float lb[4];
  for(int r=0;r<4;r++)lb[r]=__shfl(l_run,(lane>>4)*4+r);
  for(int nb=0;nb<8;nb++){
    int col=hh*128+nb*16+(lane&15);
    for(int r=0;r<4;r++){
      float o=O[nb][r]/lb[r];
      size_t rowg=(size_t)b*2048+q0+w*16+(lane>>4)*4+r;
      u16 hb=f2bf(o);
      Oh[rowg*4096+col]=hb;
      if constexpr(SPLIT) Ol[rowg*4096+col]=f2bf(o-bf2f(hb));
    }
  }
}

// ---------------- launch ----------------
extern "C" void kernel_launch(void* const* d_in, const int* in_sizes, int n_in,
                              void* d_out, int out_size, void* d_ws, size_t ws_size,
                              hipStream_t stream){
  (void)in_sizes;(void)n_in;(void)out_size;
  const float* x =(const float*)d_in[0];
  const float* wq=(const float*)d_in[1];
  const float* wk=(const float*)d_in[2];
  const float* wv=(const float*)d_in[3];
  const float* wo=(const float*)d_in[4];
  const size_t NELEM=(size_t)4096*4096;
  const size_t MAT=NELEM*sizeof(u16);                 // 32 MiB
  const size_t TAB=(size_t)2048*64*sizeof(float);     // 0.5 MiB
  const size_t need_split=10*MAT+2*TAB;               // ~321 MB
  const size_t need_bf16 = 5*MAT+2*TAB;               // ~161 MB
  if(ws_size<need_bf16)return;
  const bool split = ws_size>=need_split;
  char* ws=(char*)d_ws;
  size_t off=0;
  auto alloc=[&](size_t bytes)->char*{ char* p=ws+off; off+=bytes; return p; };
  auto allocOpt=[&](size_t bytes)->char*{ if(!split)return nullptr; char* p=ws+off; off+=bytes; return p; };
  u16* x_hi=(u16*)alloc(MAT);   u16* x_lo=(u16*)allocOpt(MAT);
  u16* w_hi=(u16*)alloc(MAT);   u16* w_lo=(u16*)allocOpt(MAT);   // reused for wq,wk,wv,wo
  u16* q_hi=(u16*)alloc(MAT);   u16* q_lo=(u16*)allocOpt(MAT);
  u16* k_hi=(u16*)alloc(MAT);   u16* k_lo=(u16*)allocOpt(MAT);
  u16* vT_hi=(u16*)alloc(MAT);  u16* vT_lo=(u16*)allocOpt(MAT);
  float* cosT=(float*)alloc(TAB);
  float* sinT=(float*)alloc(TAB);
  u16* at_hi=x_hi;  u16* at_lo=x_lo;                  // x buffers dead after V gemm

  dim3 tg(64,64), gg(32,32), ga(32,32,2);
  k_rope_tab<<<512,256,0,stream>>>(cosT,sinT);
  if(split){
    k_split<true><<<(u32)(NELEM/1024),256,0,stream>>>(x,x_hi,x_lo);
    // q = rope(x@wq) -> [B,H,S,HD]
    k_trans_split<true><<<tg,256,0,stream>>>(wq,w_hi,w_lo);
    k_gemm<1,true><<<gg,256,0,stream>>>(x_hi,x_lo,w_hi,w_lo,nullptr,q_hi,q_lo,cosT,sinT);
    // k = rope(x@wk)
    k_trans_split<true><<<tg,256,0,stream>>>(wk,w_hi,w_lo);
    k_gemm<1,true><<<gg,256,0,stream>>>(x_hi,x_lo,w_hi,w_lo,nullptr,k_hi,k_lo,cosT,sinT);
    // v^T = wv^T @ x^T  (A=wvT, BT=x) -> [d][b*S+s]
    k_trans_split<true><<<tg,256,0,stream>>>(wv,w_hi,w_lo);
    k_gemm<2,true><<<gg,256,0,stream>>>(w_hi,w_lo,x_hi,x_lo,nullptr,vT_hi,vT_lo,nullptr,nullptr);
    // attention -> at (aliases x)
    k_attn<true><<<ga,256,0,stream>>>(q_hi,q_lo,k_hi,k_lo,vT_hi,vT_lo,at_hi,at_lo);
    // out = attn @ wo (fp32)
    k_trans_split<true><<<tg,256,0,stream>>>(wo,w_hi,w_lo);
    k_gemm<3,true><<<gg,256,0,stream>>>(at_hi,at_lo,w_hi,w_lo,(float*)d_out,nullptr,nullptr,nullptr,nullptr);
  } else {
    k_split<false><<<(u32)(NELEM/1024),256,0,stream>>>(x,x_hi,nullptr);
    k_trans_split<false><<<tg,256,0,stream>>>(wq,w_hi,nullptr);
    k_gemm<1,false><<<gg,256,0,stream>>>(x_hi,nullptr,w_hi,nullptr,nullptr,q_hi,nullptr,cosT,sinT);
    k_trans_split<false><<<tg,256,0,stream>>>(wk,w_hi,nullptr);
    k_gemm<1,false><<<gg,256,0,stream>>>(x_hi,nullptr,w_hi,nullptr,nullptr,k_hi,nullptr,cosT,sinT);
    k_trans_split<false><<<tg,256,0,stream>>>(wv,w_hi,nullptr);
    k_gemm<2,false><<<gg,256,0,stream>>>(w_hi,nullptr,x_hi,nullptr,nullptr,vT_hi,nullptr,nullptr,nullptr);
    k_attn<false><<<ga,256,0,stream>>>(q_hi,nullptr,k_hi,nullptr,vT_hi,nullptr,at_hi,nullptr);
    k_trans_split<false><<<tg,256,0,stream>>>(wo,w_hi,nullptr);
    k_gemm<3,false><<<gg,256,0,stream>>>(at_hi,nullptr,w_hi,nullptr,(float*)d_out,nullptr,nullptr,nullptr,nullptr);
  }
}